// Round 1
// baseline (6607.766 us; speedup 1.0000x reference)
//
#include <hip/hip_runtime.h>
#include <hip/hip_bf16.h>

// Problem: 2-layer LSTM (T=1024, B=512, IN=20, H1=128, H2=64) + linear head OUT=3.
// KEY: reference takes h2[:, -1, :] => only batch element 511 matters.
// We compute the scan for that single batch row on ONE CU with all recurrent
// weights resident in VGPRs.

#define T_STEPS 1024
#define BATCH   512
#define IN_F    20
#define H1_     128
#define H2_     64
#define OUT_F   3
#define G1_     (4*H1_)   // 512 layer-1 gates
#define G2_     (4*H2_)   // 256 layer-2 gates

__device__ __forceinline__ float sigmoidf_(float x) {
    return 1.0f / (1.0f + __expf(-x));
}
// tanh(x) = 1 - 2/(exp(2x)+1); stable at +-inf via exp overflow->inf / underflow->0
__device__ __forceinline__ float tanhf_(float x) {
    return 1.0f - 2.0f / (__expf(2.0f * x) + 1.0f);
}

// ---------------- Kernel A: x-projection for batch row 511 -------------------
// xp1[t][g] = sum_i x[t,511,i] * W_ih0[g,i] + b_ih0[g] + b_hh0[g]
__global__ void xproj_kernel(const float* __restrict__ x,
                             const float* __restrict__ W_ih0,
                             const float* __restrict__ b_ih0,
                             const float* __restrict__ b_hh0,
                             float* __restrict__ xp1)
{
    const int t = blockIdx.x;
    const int g = threadIdx.x;
    const float* xr = x + ((size_t)t * BATCH + (BATCH - 1)) * IN_F;
    const float* w  = W_ih0 + g * IN_F;
    float acc = b_ih0[g] + b_hh0[g];
#pragma unroll
    for (int i = 0; i < IN_F; ++i) acc = fmaf(xr[i], w[i], acc);
    xp1[t * G1_ + g] = acc;
}

// ---------------- Kernel B: sequential 2-layer LSTM scan, 1 block ------------
// 512 threads (8 waves). Per thread:
//   wa[32]  : float4, W_hh0 row tid            (128 VGPRs)
//   w2[24]  : float4, layer-2 weight slice     ( 96 VGPRs)
//     tid <  256: W_ih1[o][0:96], o = tid
//     tid >= 256: W_ih1[o][96:128] (8) + W_hh1[o][0:64] (16), o = tid-256
// State: h1/h2 in LDS; c1 in reg of thread j<128; c2 in reg of thread j<64.
__global__ __launch_bounds__(512, 2)
void lstm_seq_kernel(const float* __restrict__ xp1,
                     const float* __restrict__ W_hh0,
                     const float* __restrict__ W_ih1,
                     const float* __restrict__ W_hh1,
                     const float* __restrict__ b_ih1,
                     const float* __restrict__ b_hh1,
                     float* __restrict__ h2seq)
{
    const int tid = threadIdx.x;

    __shared__ float4 sh1[H1_ / 4];   // h1[128]
    __shared__ float4 sh2[H2_ / 4];   // h2[64]
    __shared__ float  sg1[G1_];       // activated layer-1 gates
    __shared__ float  sp2[2 * G2_];   // layer-2 gate partial sums

    // ---- load resident weights into registers (fully unrolled => VGPRs) ----
    float4 wa[32];
    {
        const float4* pa = (const float4*)(W_hh0 + tid * H1_);
#pragma unroll
        for (int k = 0; k < 32; ++k) wa[k] = pa[k];
    }
    float4 w2[24];
    float  bias2 = 0.0f;
    if (tid < G2_) {
        const float4* p = (const float4*)(W_ih1 + tid * H1_);
#pragma unroll
        for (int k = 0; k < 24; ++k) w2[k] = p[k];
        bias2 = b_ih1[tid] + b_hh1[tid];
    } else {
        const int o = tid - G2_;
        const float4* p = (const float4*)(W_ih1 + o * H1_ + 96);
#pragma unroll
        for (int k = 0; k < 8; ++k) w2[k] = p[k];
        const float4* q = (const float4*)(W_hh1 + o * H2_);
#pragma unroll
        for (int k = 0; k < 16; ++k) w2[8 + k] = q[k];
    }

    // ---- init state ----
    if (tid < H1_ / 4) sh1[tid] = float4{0, 0, 0, 0};
    if (tid < H2_ / 4) sh2[tid] = float4{0, 0, 0, 0};
    float c1 = 0.0f;       // owned by tid < 128
    float c2 = 0.0f;       // owned by tid < 64
    float hh1_part = 0.0f; // owned by tid >= 256
    __syncthreads();

    float xp_next = xp1[tid];   // prefetch t=0

    for (int t = 0; t < T_STEPS; ++t) {
        const float xp_cur = xp_next;
        if (t + 1 < T_STEPS) xp_next = xp1[(t + 1) * G1_ + tid]; // hide HBM latency

        // ---- P1: layer-1 gate tid = xp + W_hh0[tid] . h1 , activated ----
        float4 a4 = {0, 0, 0, 0};
#pragma unroll
        for (int k = 0; k < 32; ++k) {
            const float4 h4 = sh1[k];
            a4.x = fmaf(wa[k].x, h4.x, a4.x);
            a4.y = fmaf(wa[k].y, h4.y, a4.y);
            a4.z = fmaf(wa[k].z, h4.z, a4.z);
            a4.w = fmaf(wa[k].w, h4.w, a4.w);
        }
        const float gate = xp_cur + ((a4.x + a4.y) + (a4.z + a4.w));
        // gates order i,f,g,o : i,f,o -> sigmoid ; g -> tanh
        const float act = (tid < 2 * H1_ || tid >= 3 * H1_) ? sigmoidf_(gate)
                                                            : tanhf_(gate);
        sg1[tid] = act;
        __syncthreads();

        // ---- P2: layer-1 pointwise (tid<128) ; overlap: W_hh1 . h2_old (tid>=256)
        if (tid < H1_) {
            const float iv = sg1[tid];
            const float fv = sg1[H1_ + tid];
            const float gv = sg1[2 * H1_ + tid];
            const float ov = sg1[3 * H1_ + tid];
            c1 = fmaf(fv, c1, iv * gv);
            const float h = ov * tanhf_(c1);
            ((float*)sh1)[tid] = h;
        } else if (tid >= G2_) {
            float4 s4 = {0, 0, 0, 0};
#pragma unroll
            for (int k = 0; k < 16; ++k) {
                const float4 h4 = sh2[k];
                s4.x = fmaf(w2[8 + k].x, h4.x, s4.x);
                s4.y = fmaf(w2[8 + k].y, h4.y, s4.y);
                s4.z = fmaf(w2[8 + k].z, h4.z, s4.z);
                s4.w = fmaf(w2[8 + k].w, h4.w, s4.w);
            }
            hh1_part = (s4.x + s4.y) + (s4.z + s4.w);
        }
        __syncthreads();

        // ---- P3: layer-2 gate partials over h1_new ----
        float p2v;
        if (tid < G2_) {
            float4 a = {0, 0, 0, 0};
#pragma unroll
            for (int k = 0; k < 24; ++k) {
                const float4 h4 = sh1[k];
                a.x = fmaf(w2[k].x, h4.x, a.x);
                a.y = fmaf(w2[k].y, h4.y, a.y);
                a.z = fmaf(w2[k].z, h4.z, a.z);
                a.w = fmaf(w2[k].w, h4.w, a.w);
            }
            p2v = bias2 + ((a.x + a.y) + (a.z + a.w));
        } else {
            float4 a = {0, 0, 0, 0};
#pragma unroll
            for (int k = 0; k < 8; ++k) {
                const float4 h4 = sh1[24 + k];
                a.x = fmaf(w2[k].x, h4.x, a.x);
                a.y = fmaf(w2[k].y, h4.y, a.y);
                a.z = fmaf(w2[k].z, h4.z, a.z);
                a.w = fmaf(w2[k].w, h4.w, a.w);
            }
            p2v = hh1_part + ((a.x + a.y) + (a.z + a.w));
        }
        sp2[tid] = p2v;
        __syncthreads();

        // ---- P4/5: layer-2 pointwise (tid<64) ----
        if (tid < H2_) {
            const float iv = sigmoidf_(sp2[tid]            + sp2[G2_ + tid]);
            const float fv = sigmoidf_(sp2[H2_ + tid]      + sp2[G2_ + H2_ + tid]);
            const float gv = tanhf_   (sp2[2 * H2_ + tid]  + sp2[G2_ + 2 * H2_ + tid]);
            const float ov = sigmoidf_(sp2[3 * H2_ + tid]  + sp2[G2_ + 3 * H2_ + tid]);
            c2 = fmaf(fv, c2, iv * gv);
            const float h = ov * tanhf_(c2);
            ((float*)sh2)[tid] = h;
            h2seq[t * H2_ + tid] = h;   // fire-and-forget store
        }
        __syncthreads();
    }
}

// ---------------- Kernel C: output head out[t,o] = relu(h2[t]) . W_d[o] + b_d
__global__ void head_kernel(const float* __restrict__ h2seq,
                            const float* __restrict__ W_d,
                            const float* __restrict__ b_d,
                            float* __restrict__ out)
{
    const int idx = blockIdx.x * blockDim.x + threadIdx.x;
    if (idx >= T_STEPS * OUT_F) return;
    const int t = idx / OUT_F;
    const int o = idx - t * OUT_F;
    const float* hr = h2seq + t * H2_;
    const float* w  = W_d + o * H2_;
    float acc = b_d[o];
#pragma unroll
    for (int j = 0; j < H2_; ++j) acc = fmaf(fmaxf(hr[j], 0.0f), w[j], acc);
    out[idx] = acc;
}

extern "C" void kernel_launch(void* const* d_in, const int* in_sizes, int n_in,
                              void* d_out, int out_size, void* d_ws, size_t ws_size,
                              hipStream_t stream) {
    const float* x     = (const float*)d_in[0];
    const float* W_ih0 = (const float*)d_in[1];
    const float* W_hh0 = (const float*)d_in[2];
    const float* b_ih0 = (const float*)d_in[3];
    const float* b_hh0 = (const float*)d_in[4];
    const float* W_ih1 = (const float*)d_in[5];
    const float* W_hh1 = (const float*)d_in[6];
    const float* b_ih1 = (const float*)d_in[7];
    const float* b_hh1 = (const float*)d_in[8];
    const float* W_d   = (const float*)d_in[9];
    const float* b_d   = (const float*)d_in[10];

    float* out   = (float*)d_out;
    float* xp1   = (float*)d_ws;               // [1024][512] f32 = 2 MB
    float* h2seq = xp1 + (size_t)T_STEPS * G1_; // [1024][64]  f32 = 256 KB

    hipLaunchKernelGGL(xproj_kernel, dim3(T_STEPS), dim3(G1_), 0, stream,
                       x, W_ih0, b_ih0, b_hh0, xp1);
    hipLaunchKernelGGL(lstm_seq_kernel, dim3(1), dim3(512), 0, stream,
                       xp1, W_hh0, W_ih1, W_hh1, b_ih1, b_hh1, h2seq);
    hipLaunchKernelGGL(head_kernel, dim3((T_STEPS * OUT_F + 255) / 256), dim3(256),
                       0, stream, h2seq, W_d, b_d, out);
}